// Round 5
// baseline (12833.568 us; speedup 1.0000x reference)
//
#include <hip/hip_runtime.h>
#include <math.h>

// Problem constants: B=8, S=16, CIN=128, H=W=64, D=64
// Padded field layout for conv inputs: [b][c][66 rows][72 cols], value(x,y) at [y+1][x+4],
// borders zero. PF = 8*64*66*72 = 2,433,024 floats.

__device__ __forceinline__ float sigf(float x){ return 1.0f/(1.0f + expf(-x)); }

#define FMA4(A, W, V0, V1, V2, V3) { (A).x += (W)*(V0); (A).y += (W)*(V1); (A).z += (W)*(V2); (A).w += (W)*(V3); }

// ---------------------------------------------------------------------------
// reshape clstm_w (256,128,3,3) -> w2[(ic*9+k)*256 + oc]
__global__ __launch_bounds__(256) void k_w2(const float* __restrict__ cw, float* __restrict__ w2){
    int idx = blockIdx.x*256 + threadIdx.x;
    if (idx < 128*9*256){
        int oc = idx & 255;
        int r  = idx >> 8;           // r = ic*9 + k
        w2[idx] = cw[oc*1152 + r];
    }
}

// ---------------------------------------------------------------------------
// 1x1 proj conv + BN partial sums. Writes raw t==0 slice into x0 buffer.
__global__ __launch_bounds__(256) void k_proj(const float* __restrict__ x, const float* __restrict__ pw,
                                              float* __restrict__ x0raw, float* __restrict__ psum,
                                              float* __restrict__ psumsq){
    __shared__ __align__(16) float smem[8192];
    const int tile = blockIdx.x;
    const int n    = blockIdx.y;
    const int tid  = threadIdx.x;
    const int pj = tid & 63, dg = tid >> 6;

    for (int r = tid; r < 8192; r += 256){
        int c = r >> 6, d = r & 63;
        smem[r] = pw[d*128 + c];
    }
    __syncthreads();

    const int p0 = tile*256 + pj*4;
    float4 acc[16];
#pragma unroll
    for (int i=0;i<16;i++) acc[i] = make_float4(0.f,0.f,0.f,0.f);

    const float* xb = x + (((size_t)n) << 19) + p0;
    for (int c = 0; c < 128; ++c){
        float4 xv = *(const float4*)(xb + ((size_t)c << 12));
        const float4* wr = (const float4*)(smem + c*64 + dg*16);
#pragma unroll
        for (int q=0;q<4;++q){
            float4 w4 = wr[q];
            FMA4(acc[q*4+0], w4.x, xv.x, xv.y, xv.z, xv.w);
            FMA4(acc[q*4+1], w4.y, xv.x, xv.y, xv.z, xv.w);
            FMA4(acc[q*4+2], w4.z, xv.x, xv.y, xv.z, xv.w);
            FMA4(acc[q*4+3], w4.w, xv.x, xv.y, xv.z, xv.w);
        }
    }

    const int t = n & 15, b = n >> 4;
    if (t == 0){
#pragma unroll
        for (int i=0;i<16;i++){
            int dd = dg*16 + i;
            *(float4*)(x0raw + (((size_t)(b*64 + dd)) << 12) + p0) = acc[i];
        }
    }
    float ls[16], lss[16];
#pragma unroll
    for (int i=0;i<16;i++){
        float4 a = acc[i];
        ls[i]  = a.x + a.y + a.z + a.w;
        lss[i] = a.x*a.x + a.y*a.y + a.z*a.z + a.w*a.w;
    }
    __syncthreads();
#pragma unroll
    for (int i=0;i<16;i++) smem[pj*65 + dg*16 + i] = ls[i];
    __syncthreads();
    if (tid < 64){
        float s = 0.f;
        for (int p=0;p<64;p++) s += smem[p*65 + tid];
        psum[((n*16 + tile) << 6) + tid] = s;
    }
    __syncthreads();
#pragma unroll
    for (int i=0;i<16;i++) smem[pj*65 + dg*16 + i] = lss[i];
    __syncthreads();
    if (tid < 64){
        float s = 0.f;
        for (int p=0;p<64;p++) s += smem[p*65 + tid];
        psumsq[((n*16 + tile) << 6) + tid] = s;
    }
}

// ---------------------------------------------------------------------------
__global__ __launch_bounds__(64) void k_bnfinal(const float* __restrict__ psum, const float* __restrict__ psumsq,
                                                const float* __restrict__ gamma, const float* __restrict__ beta,
                                                float* __restrict__ scale, float* __restrict__ shift,
                                                float* __restrict__ xmean){
    const int d = threadIdx.x;
    double gs = 0.0, gss = 0.0;
    for (int n=0;n<128;n++){
        float s = 0.f, ss = 0.f;
        for (int tl=0;tl<16;tl++){
            s  += psum  [((n*16+tl)<<6) + d];
            ss += psumsq[((n*16+tl)<<6) + d];
        }
        gs += (double)s; gss += (double)ss;
    }
    double mu  = gs  / 524288.0;
    double var = gss / 524288.0 - mu*mu;
    double sc  = (double)gamma[d] / sqrt(var + 1e-5);
    float scf = (float)sc;
    float shf = (float)((double)beta[d] - mu*sc);
    scale[d] = scf; shift[d] = shf;
    for (int n=0;n<128;n++){
        float s = 0.f;
        for (int tl=0;tl<16;tl++) s += psum[((n*16+tl)<<6) + d];
        xmean[(n<<6) + d] = (s * (1.f/4096.f)) * scf + shf;
    }
}

// ---------------------------------------------------------------------------
// Zero a float4-multiple region (yhat_p | hfA_p | hfB_p | cf, contiguous).
__global__ __launch_bounds__(256) void k_zero(float* __restrict__ z){
    size_t i = ((size_t)blockIdx.x*256 + threadIdx.x)*4;
    *(float4*)(z + i) = make_float4(0.f,0.f,0.f,0.f);
}

// ---------------------------------------------------------------------------
// Apply BN to x0 (in place), write yhat_p interior, init states, P=P_init.
__global__ __launch_bounds__(256) void k_init(const float* __restrict__ scale, const float* __restrict__ shift,
                                              float* __restrict__ x0, float* __restrict__ yhat_p,
                                              const float* __restrict__ Pinit, float* __restrict__ Pg,
                                              float* __restrict__ hQ, float* __restrict__ cQ,
                                              float* __restrict__ hR, float* __restrict__ cR){
    size_t idx = (size_t)blockIdx.x*256 + threadIdx.x;   // 2,097,152 total
    int d = (int)((idx >> 12) & 63);
    float v = x0[idx]*scale[d] + shift[d];
    x0[idx] = v;
    int b = (int)(idx >> 18), r = (int)((idx >> 6) & 63), xx = (int)(idx & 63);
    yhat_p[(((size_t)(b*64 + d))*66 + r + 1)*72 + xx + 4] = v;
    if (idx < 512){ hQ[idx]=0.f; cQ[idx]=0.f; hR[idx]=0.f; cR[idx]=0.f; }
    if (idx < 32768) Pg[idx] = Pinit[idx & 4095];
}

// ---------------------------------------------------------------------------
// ConvLSTM step. grid (32 row-pairs, 8 b), block 256, 1 block/CU.
// Thread: 8 px (one row-half) x 16 oc (4 gates x 4 d) -> acc 128 floats.
// Double-buffered chunks of 2 ic; padded inputs (no bounds checks); in-reg gating.
__global__ __launch_bounds__(256,1) void k_conv(const float* __restrict__ yhat_p, const float* __restrict__ hfin_p,
                                                float* __restrict__ hfout_p, float* __restrict__ cf,
                                                const float* __restrict__ w2, const float* __restrict__ cb,
                                                float* __restrict__ hfpart){
    // LDS: red[1040] | wbuf[2][4608] | ibuf[2][576]
    __shared__ __align__(16) float smem[11408];
    const int RED = 0, WB = 1040, IB = 10256;
    const int rp2 = blockIdx.x*2;
    const int b   = blockIdx.y;
    const int tid = threadIdx.x;
    const int pxq = tid & 15;         // 16 px-groups: sub-row (>>3), px-half (&7)
    const int ocq = tid >> 4;         // 16 oc-groups: d0 = ocq*4, oc = g*64+d0+e
    const int d0  = ocq*4;
    const int sub = pxq >> 3;
    const int px0 = (pxq & 7)*8;
    const int row = rp2 + sub;

    float4 acc4[32];                  // [(g*4+e)*2 + h], h = px 0-3 / 4-7
#pragma unroll
    for (int i=0;i<32;i++) acc4[i] = make_float4(0.f,0.f,0.f,0.f);

    // staging: 1296 float4 slots per chunk = w 1152 (2 ic x 9 k x 256 oc) + in 144 (2 ic x 4 rows x 72)
    float4 st[6];
    auto issue = [&](int icc){
#pragma unroll
        for (int j=0;j<5;++j){
            int s = tid + j*256;
            const float* src;
            if (s < 1152){
                src = w2 + (size_t)icc*4608 + (size_t)s*4;
            } else {
                int si  = s - 1152;
                int icl = (si >= 72) ? 1 : 0;
                int sl  = si - icl*72;
                int ic  = icc*2 + icl;
                const float* f = (ic < 64) ? yhat_p : hfin_p;
                src = f + (((size_t)(b*64 + (ic & 63)))*66 + rp2)*72 + (size_t)sl*4;
            }
            st[j] = *(const float4*)src;
        }
        if (tid < 16){
            int si = 128 + tid;                 // icl = 1, sl = si-72
            int ic = icc*2 + 1;
            const float* f = (ic < 64) ? yhat_p : hfin_p;
            st[5] = *(const float4*)(f + (((size_t)(b*64 + (ic & 63)))*66 + rp2)*72 + (size_t)(si-72)*4);
        }
    };
    auto commit = [&](int buf){
#pragma unroll
        for (int j=0;j<5;++j){
            int s = tid + j*256;
            if (s < 1152) *(float4*)(smem + WB + buf*4608 + s*4) = st[j];
            else          *(float4*)(smem + IB + buf*576 + (s-1152)*4) = st[j];
        }
        if (tid < 16)     *(float4*)(smem + IB + buf*576 + (size_t)(128+tid)*4) = st[5];
    };

    issue(0); commit(0); __syncthreads();

    int p = 0;
    for (int icc = 0; icc < 64; ++icc){
        if (icc < 63) issue(icc + 1);      // loads in flight under compute

        const float* wb = smem + WB + p*4608;
        const float* ib = smem + IB + p*576;
#pragma unroll
        for (int icl = 0; icl < 2; ++icl){
#pragma unroll
            for (int ky = 0; ky < 3; ++ky){
                const float* vp = ib + icl*288 + (sub+ky)*72 + px0;
                float v[10];
                {
                    float  s0 = vp[3];
                    float4 va = *(const float4*)(vp + 4);
                    float4 vb = *(const float4*)(vp + 8);
                    float  s1 = vp[12];
                    v[0]=s0; v[1]=va.x; v[2]=va.y; v[3]=va.z; v[4]=va.w;
                    v[5]=vb.x; v[6]=vb.y; v[7]=vb.z; v[8]=vb.w; v[9]=s1;
                }
#pragma unroll
                for (int kx = 0; kx < 3; ++kx){
                    const float* wrow = wb + ((icl*9 + ky*3 + kx) << 8) + d0;
#pragma unroll
                    for (int g = 0; g < 4; ++g){
                        float4 w4 = *(const float4*)(wrow + (g << 6));
                        int ba = g*8;
                        FMA4(acc4[ba+0], w4.x, v[kx+0],v[kx+1],v[kx+2],v[kx+3]);
                        FMA4(acc4[ba+1], w4.x, v[kx+4],v[kx+5],v[kx+6],v[kx+7]);
                        FMA4(acc4[ba+2], w4.y, v[kx+0],v[kx+1],v[kx+2],v[kx+3]);
                        FMA4(acc4[ba+3], w4.y, v[kx+4],v[kx+5],v[kx+6],v[kx+7]);
                        FMA4(acc4[ba+4], w4.z, v[kx+0],v[kx+1],v[kx+2],v[kx+3]);
                        FMA4(acc4[ba+5], w4.z, v[kx+4],v[kx+5],v[kx+6],v[kx+7]);
                        FMA4(acc4[ba+6], w4.w, v[kx+0],v[kx+1],v[kx+2],v[kx+3]);
                        FMA4(acc4[ba+7], w4.w, v[kx+4],v[kx+5],v[kx+6],v[kx+7]);
                    }
                }
            }
        }

        if (icc < 63) commit(p ^ 1);       // vmcnt drained here, hidden by compute
        __syncthreads();
        p ^= 1;
    }

    // ---- gating fully in registers: gate order i,f,o,g ----
#pragma unroll
    for (int e = 0; e < 4; ++e){
        const int d = d0 + e;
        const float biv = cb[d], bfv = cb[64+d], bov = cb[128+d], bgv = cb[192+d];
        float4 zi0 = acc4[(0*4+e)*2+0], zi1 = acc4[(0*4+e)*2+1];
        float4 zf0 = acc4[(1*4+e)*2+0], zf1 = acc4[(1*4+e)*2+1];
        float4 zo0 = acc4[(2*4+e)*2+0], zo1 = acc4[(2*4+e)*2+1];
        float4 zg0 = acc4[(3*4+e)*2+0], zg1 = acc4[(3*4+e)*2+1];
        zi0.x+=biv; zi0.y+=biv; zi0.z+=biv; zi0.w+=biv; zi1.x+=biv; zi1.y+=biv; zi1.z+=biv; zi1.w+=biv;
        zf0.x+=bfv; zf0.y+=bfv; zf0.z+=bfv; zf0.w+=bfv; zf1.x+=bfv; zf1.y+=bfv; zf1.z+=bfv; zf1.w+=bfv;
        zo0.x+=bov; zo0.y+=bov; zo0.z+=bov; zo0.w+=bov; zo1.x+=bov; zo1.y+=bov; zo1.z+=bov; zo1.w+=bov;
        zg0.x+=bgv; zg0.y+=bgv; zg0.z+=bgv; zg0.w+=bgv; zg1.x+=bgv; zg1.y+=bgv; zg1.z+=bgv; zg1.w+=bgv;

        size_t gidx = (((size_t)(b*64 + d)) << 12) + row*64 + px0;
        float4 c0 = *(const float4*)(cf + gidx);
        float4 c1 = *(const float4*)(cf + gidx + 4);
        float4 n0, n1, h0, h1;
        n0.x = sigf(zf0.x)*c0.x + sigf(zi0.x)*tanhf(zg0.x); h0.x = sigf(zo0.x)*tanhf(n0.x);
        n0.y = sigf(zf0.y)*c0.y + sigf(zi0.y)*tanhf(zg0.y); h0.y = sigf(zo0.y)*tanhf(n0.y);
        n0.z = sigf(zf0.z)*c0.z + sigf(zi0.z)*tanhf(zg0.z); h0.z = sigf(zo0.z)*tanhf(n0.z);
        n0.w = sigf(zf0.w)*c0.w + sigf(zi0.w)*tanhf(zg0.w); h0.w = sigf(zo0.w)*tanhf(n0.w);
        n1.x = sigf(zf1.x)*c1.x + sigf(zi1.x)*tanhf(zg1.x); h1.x = sigf(zo1.x)*tanhf(n1.x);
        n1.y = sigf(zf1.y)*c1.y + sigf(zi1.y)*tanhf(zg1.y); h1.y = sigf(zo1.y)*tanhf(n1.y);
        n1.z = sigf(zf1.z)*c1.z + sigf(zi1.z)*tanhf(zg1.z); h1.z = sigf(zo1.z)*tanhf(n1.z);
        n1.w = sigf(zf1.w)*c1.w + sigf(zi1.w)*tanhf(zg1.w); h1.w = sigf(zo1.w)*tanhf(n1.w);
        *(float4*)(cf + gidx)     = n0;
        *(float4*)(cf + gidx + 4) = n1;
        size_t pidx = (((size_t)(b*64 + d))*66 + row + 1)*72 + px0 + 4;
        *(float4*)(hfout_p + pidx)     = h0;
        *(float4*)(hfout_p + pidx + 4) = h1;
        smem[RED + pxq*65 + d] = h0.x+h0.y+h0.z+h0.w + h1.x+h1.y+h1.z+h1.w;
    }
    __syncthreads();
    if (tid < 128){
        int d = tid & 63, rs = tid >> 6;
        float s = 0.f;
#pragma unroll
        for (int q=0;q<8;q++) s += smem[RED + (rs*8 + q)*65 + d];
        hfpart[((b*64 + rp2 + rs) << 6) + d] = s;
    }
}

// ---------------------------------------------------------------------------
// y_tick = fcf(hf) per position + spatial partial sums. grid (16,8), block 256.
// Reads hf from the PADDED field.
__global__ __launch_bounds__(256) void k_ytick(const float* __restrict__ hf_p, const float* __restrict__ fw,
                                               const float* __restrict__ fb, float* __restrict__ ytick,
                                               float* __restrict__ ytpart){
    __shared__ __align__(16) float wsm[4096];
    __shared__ float red[4160];
    const int tile = blockIdx.x;
    const int b    = blockIdx.y;
    const int tid  = threadIdx.x;
    const int pj = tid & 63, dg = tid >> 6;

    for (int r = tid; r < 4096; r += 256){
        int e = r >> 6, dd = r & 63;
        wsm[r] = fw[dd*64 + e];
    }
    __syncthreads();

    const int p0 = tile*256 + pj*4;
    const int r = p0 >> 6, xx = p0 & 63;
    float4 acc[16];
#pragma unroll
    for (int i=0;i<16;i++) acc[i] = make_float4(0.f,0.f,0.f,0.f);

    const float* hb = hf_p + (((size_t)(b*64))*66 + r + 1)*72 + xx + 4;
    for (int e = 0; e < 64; ++e){
        float4 hv = *(const float4*)(hb + (size_t)e*4752);   // 66*72
        const float4* wr = (const float4*)(wsm + e*64 + dg*16);
#pragma unroll
        for (int q=0;q<4;++q){
            float4 w4 = wr[q];
            FMA4(acc[q*4+0], w4.x, hv.x, hv.y, hv.z, hv.w);
            FMA4(acc[q*4+1], w4.y, hv.x, hv.y, hv.z, hv.w);
            FMA4(acc[q*4+2], w4.z, hv.x, hv.y, hv.z, hv.w);
            FMA4(acc[q*4+3], w4.w, hv.x, hv.y, hv.z, hv.w);
        }
    }
    float ls[16];
#pragma unroll
    for (int i=0;i<16;i++){
        int dd = dg*16 + i;
        float bv = fb[dd];
        acc[i].x += bv; acc[i].y += bv; acc[i].z += bv; acc[i].w += bv;
        *(float4*)(ytick + (((size_t)(b*64 + dd)) << 12) + p0) = acc[i];
        ls[i] = acc[i].x + acc[i].y + acc[i].z + acc[i].w;
    }
#pragma unroll
    for (int i=0;i<16;i++) red[pj*65 + dg*16 + i] = ls[i];
    __syncthreads();
    if (tid < 64){
        float s = 0.f;
        for (int p=0;p<64;p++) s += red[p*65 + tid];
        ytpart[((b*16 + tile) << 6) + tid] = s;
    }
}

// ---------------------------------------------------------------------------
// Per-step small ops + Kalman update. grid 8 (b), block 256.
__global__ __launch_bounds__(256) void k_small(int t,
        const float* __restrict__ hfpart, const float* __restrict__ ytpart, const float* __restrict__ xmean,
        const float* __restrict__ fcF_w, const float* __restrict__ fcF_b,
        const float* __restrict__ lq_wih, const float* __restrict__ lq_whh,
        const float* __restrict__ lq_bih, const float* __restrict__ lq_bhh,
        const float* __restrict__ lr_wih, const float* __restrict__ lr_whh,
        const float* __restrict__ lr_bih, const float* __restrict__ lr_bhh,
        const float* __restrict__ fcQ_w, const float* __restrict__ fcQ_b,
        const float* __restrict__ fcR_w, const float* __restrict__ fcR_b,
        float* __restrict__ hQ, float* __restrict__ cQ, float* __restrict__ hR, float* __restrict__ cR,
        float* __restrict__ Pg, float* __restrict__ Kg){
    const int b = blockIdx.x, tid = threadIdx.x;
    __shared__ __align__(16) float aug[64*132];
    __shared__ __align__(16) float Pl[4096];
    __shared__ float hfm[64], ytm[64], xm[64], Fv[64], Qd[64], Rd[64], rds[64];
    __shared__ float hq_s[64], cq_s[64], hr_s[64], cr_s[64];
    __shared__ float gq[256], gr[256];

    if (tid < 64){
        float s = 0.f;
        for (int r=0;r<64;r++) s += hfpart[((b*64 + r) << 6) + tid];
        hfm[tid] = s * (1.f/4096.f);
        float s2 = 0.f;
        for (int r=0;r<16;r++) s2 += ytpart[((b*16 + r) << 6) + tid];
        ytm[tid] = s2 * (1.f/4096.f);
        xm[tid] = xmean[((b*16 + t) << 6) + tid];
        hq_s[tid] = hQ[b*64+tid]; cq_s[tid] = cQ[b*64+tid];
        hr_s[tid] = hR[b*64+tid]; cr_s[tid] = cR[b*64+tid];
    }
    __syncthreads();
    {
        int j = tid;
        float aq = lq_bih[j] + lq_bhh[j];
        float ar = lr_bih[j] + lr_bhh[j];
        for (int e=0;e<64;e++){
            aq += lq_wih[j*64+e]*ytm[e] + lq_whh[j*64+e]*hq_s[e];
            ar += lr_wih[j*64+e]*xm[e]  + lr_whh[j*64+e]*hr_s[e];
        }
        gq[j] = aq; gr[j] = ar;
    }
    if (tid < 64){
        float a = fcF_b[tid];
        for (int e=0;e<64;e++) a += fcF_w[tid*64+e]*hfm[e];
        Fv[tid] = a;
    }
    __syncthreads();
    if (tid < 64){   // lstm_cell gate order: i, f, g, o
        int dd = tid;
        float gi = gq[dd], gf = gq[64+dd], gg = gq[128+dd], go = gq[192+dd];
        float c2 = sigf(gf)*cq_s[dd] + sigf(gi)*tanhf(gg);
        float h2 = sigf(go)*tanhf(c2);
        cq_s[dd] = c2; hq_s[dd] = h2;
        gi = gr[dd]; gf = gr[64+dd]; gg = gr[128+dd]; go = gr[192+dd];
        c2 = sigf(gf)*cr_s[dd] + sigf(gi)*tanhf(gg);
        h2 = sigf(go)*tanhf(c2);
        cr_s[dd] = c2; hr_s[dd] = h2;
    }
    __syncthreads();
    if (tid < 64){
        float aq_ = fcQ_b[tid], ar_ = fcR_b[tid];
        for (int e=0;e<64;e++){ aq_ += fcQ_w[tid*64+e]*hq_s[e]; ar_ += fcR_w[tid*64+e]*hr_s[e]; }
        Qd[tid] = expf(aq_); Rd[tid] = expf(ar_);
        hQ[b*64+tid] = hq_s[tid]; cQ[b*64+tid] = cq_s[tid];
        hR[b*64+tid] = hr_s[tid]; cR[b*64+tid] = cr_s[tid];
    }
    __syncthreads();
    // P = P*FF + diag(Qd); aug = [A=P+diag(Rd) | P]
    for (int r = tid; r < 4096; r += 256){
        int i = r >> 6, j = r & 63;
        float p = Pg[((size_t)b << 12) + r] * Fv[i]*Fv[j] + (i==j ? Qd[i] : 0.f);
        Pl[r] = p;
        aug[i*132 + 64 + j] = p;
        aug[i*132 + j]      = p + (i==j ? Rd[i] : 0.f);
    }
    __syncthreads();
    const int r_ = tid & 63, cq_ = tid >> 6;
    for (int k = 0; k < 64; ++k){
        float akk = aug[k*132 + k];
        float f = aug[r_*132 + k] / akk;
        if (r_ != k){
#pragma unroll
            for (int u = 0; u < 8; ++u){
                int c4 = cq_*32 + u*4;
                if (c4 + 3 > k){
                    float4 pv = *(const float4*)(aug + k*132 + c4);
                    float4 av = *(const float4*)(aug + r_*132 + c4);
                    av.x = (c4+0 > k) ? av.x - f*pv.x : av.x;
                    av.y = (c4+1 > k) ? av.y - f*pv.y : av.y;
                    av.z = (c4+2 > k) ? av.z - f*pv.z : av.z;
                    av.w = (c4+3 > k) ? av.w - f*pv.w : av.w;
                    *(float4*)(aug + r_*132 + c4) = av;
                }
            }
        }
        __syncthreads();
    }
    if (tid < 64) rds[tid] = 1.0f / aug[tid*132 + tid];
    __syncthreads();
    {
        const int i = tid >> 2, jq = tid & 3;
        float4 tv[4];
#pragma unroll
        for (int q=0;q<4;++q) tv[q] = *(const float4*)(Pl + i*64 + jq*16 + q*4);
        for (int m=0;m<64;++m){
            float kim = aug[m*132 + 64 + i] * rds[m];
#pragma unroll
            for (int q=0;q<4;++q){
                float4 pv = *(const float4*)(Pl + m*64 + jq*16 + q*4);
                tv[q].x -= kim*pv.x; tv[q].y -= kim*pv.y; tv[q].z -= kim*pv.z; tv[q].w -= kim*pv.w;
            }
        }
#pragma unroll
        for (int q=0;q<4;++q) *(float4*)(aug + i*132 + jq*16 + q*4) = tv[q];
    }
    __syncthreads();
    {
        const int i = tid >> 2, jq = tid & 3;
        float4 a2[4];
#pragma unroll
        for (int q=0;q<4;++q) a2[q] = *(const float4*)(aug + i*132 + jq*16 + q*4);
        for (int m=0;m<64;++m){
            float t1im = aug[i*132 + m];
            float kim  = aug[m*132 + 64 + i] * rds[m];
            float coef = rds[m] * (kim * Rd[m] - t1im);
#pragma unroll
            for (int q=0;q<4;++q){
                float4 yv = *(const float4*)(aug + m*132 + 64 + jq*16 + q*4);
                a2[q].x += coef*yv.x; a2[q].y += coef*yv.y; a2[q].z += coef*yv.z; a2[q].w += coef*yv.w;
            }
        }
        size_t base = ((size_t)b << 12) + (size_t)i*64;
#pragma unroll
        for (int q=0;q<4;++q) *(float4*)(Pg + base + jq*16 + q*4) = a2[q];
#pragma unroll
        for (int q=0;q<4;++q){
#pragma unroll
            for (int e=0;e<4;++e){
                int j = jq*16 + q*4 + e;
                Kg[base + j] = aug[j*132 + 64 + i] * rds[j];
            }
        }
    }
}

// ---------------------------------------------------------------------------
// y_hat = y_tick + K(x0 - y_tick); writes PADDED yhat + spatial partial sums.
__global__ __launch_bounds__(256) void k_apply(int t, const float* __restrict__ ytick,
                                               const float* __restrict__ x0, const float* __restrict__ Kg,
                                               float* __restrict__ yhat_p, float* __restrict__ featpart){
    __shared__ __align__(16) float kt[4096];
    __shared__ float red[4160];
    const int tile = blockIdx.x;
    const int b    = blockIdx.y;
    const int tid  = threadIdx.x;
    const int pj = tid & 63, dg = tid >> 6;

    for (int r = tid; r < 4096; r += 256){
        int i = r >> 6, j = r & 63;
        kt[j*64 + i] = Kg[((size_t)b << 12) + r];
    }
    __syncthreads();

    const int p0 = tile*256 + pj*4;
    const int r = p0 >> 6, xx = p0 & 63;
    float4 acc[16];
#pragma unroll
    for (int i=0;i<16;i++) acc[i] = make_float4(0.f,0.f,0.f,0.f);

    for (int j = 0; j < 64; ++j){
        size_t gi = (((size_t)(b*64 + j)) << 12) + p0;
        float4 xv = *(const float4*)(x0 + gi);
        float4 yv = *(const float4*)(ytick + gi);
        float u0 = xv.x - yv.x, u1 = xv.y - yv.y, u2 = xv.z - yv.z, u3 = xv.w - yv.w;
        const float4* wr = (const float4*)(kt + j*64 + dg*16);
#pragma unroll
        for (int q=0;q<4;++q){
            float4 k4 = wr[q];
            FMA4(acc[q*4+0], k4.x, u0,u1,u2,u3);
            FMA4(acc[q*4+1], k4.y, u0,u1,u2,u3);
            FMA4(acc[q*4+2], k4.z, u0,u1,u2,u3);
            FMA4(acc[q*4+3], k4.w, u0,u1,u2,u3);
        }
    }
    float ls[16];
#pragma unroll
    for (int i=0;i<16;i++){
        int dd = dg*16 + i;
        size_t gi = (((size_t)(b*64 + dd)) << 12) + p0;
        float4 yv = *(const float4*)(ytick + gi);
        float4 o;
        o.x = yv.x + acc[i].x; o.y = yv.y + acc[i].y; o.z = yv.z + acc[i].z; o.w = yv.w + acc[i].w;
        *(float4*)(yhat_p + (((size_t)(b*64 + dd))*66 + r + 1)*72 + xx + 4) = o;
        ls[i] = o.x + o.y + o.z + o.w;
    }
#pragma unroll
    for (int i=0;i<16;i++) red[pj*65 + dg*16 + i] = ls[i];
    __syncthreads();
    if (tid < 64){
        float s = 0.f;
        for (int p=0;p<64;p++) s += red[p*65 + tid];
        featpart[(((size_t)((t*8 + b)*16 + tile)) << 6) + tid] = s;
    }
}

// ---------------------------------------------------------------------------
__global__ __launch_bounds__(64) void k_head(const float* __restrict__ featpart,
                                             const float* __restrict__ fc_w, const float* __restrict__ fc_b,
                                             const float* __restrict__ fco_w, const float* __restrict__ fco_b,
                                             const float* __restrict__ fca_w, const float* __restrict__ fca_b,
                                             float* __restrict__ out){
    const int bt = blockIdx.x;
    const int b = bt >> 4, t = bt & 15;
    __shared__ float fs[64];
    const int i = threadIdx.x;
    float s = 0.f;
    for (int tile=0;tile<16;tile++) s += featpart[(((size_t)((t*8 + b)*16 + tile)) << 6) + i];
    fs[i] = s * (1.f/4096.f);
    __syncthreads();
    float a = fc_b[i];
    for (int e=0;e<64;e++) a += fc_w[i*64+e]*fs[e];
    a = fmaxf(a, 0.f);
    float po = a * fco_w[i];
    float pa = a * fca_w[i];
    for (int off=32; off; off >>= 1){ po += __shfl_down(po, off); pa += __shfl_down(pa, off); }
    if (i == 0){
        out[bt]       = po + fco_b[0];
        out[128 + bt] = pa + fca_b[0];
    }
}

// ---------------------------------------------------------------------------
extern "C" void kernel_launch(void* const* d_in, const int* in_sizes, int n_in,
                              void* d_out, int out_size, void* d_ws, size_t ws_size,
                              hipStream_t stream){
    const float* x       = (const float*)d_in[0];
    const float* proj_w  = (const float*)d_in[1];
    const float* bn_g    = (const float*)d_in[2];
    const float* bn_b    = (const float*)d_in[3];
    const float* clstm_w = (const float*)d_in[4];
    const float* clstm_b = (const float*)d_in[5];
    const float* lq_wih  = (const float*)d_in[6];
    const float* lq_whh  = (const float*)d_in[7];
    const float* lq_bih  = (const float*)d_in[8];
    const float* lq_bhh  = (const float*)d_in[9];
    const float* lr_wih  = (const float*)d_in[10];
    const float* lr_whh  = (const float*)d_in[11];
    const float* lr_bih  = (const float*)d_in[12];
    const float* lr_bhh  = (const float*)d_in[13];
    const float* fcf_w   = (const float*)d_in[14];
    const float* fcf_b   = (const float*)d_in[15];
    const float* fcF_w   = (const float*)d_in[16];
    const float* fcF_b   = (const float*)d_in[17];
    const float* fcQ_w   = (const float*)d_in[18];
    const float* fcQ_b   = (const float*)d_in[19];
    const float* fcR_w   = (const float*)d_in[20];
    const float* fcR_b   = (const float*)d_in[21];
    const float* P_init  = (const float*)d_in[22];
    const float* fc_w    = (const float*)d_in[23];
    const float* fc_b    = (const float*)d_in[24];
    const float* fco_w   = (const float*)d_in[25];
    const float* fco_b   = (const float*)d_in[26];
    const float* fca_w   = (const float*)d_in[27];
    const float* fca_b   = (const float*)d_in[28];
    float* out = (float*)d_out;
    float* ws  = (float*)d_ws;

    const size_t PF    = 2433024;        // 8*64*66*72 padded field
    const size_t FIELD = 2097152;        // 8*64*4096
    float* yhat_p = ws;                  // PF
    float* hfA_p  = ws + PF;             // PF
    float* hfB_p  = ws + 2*PF;           // PF
    float* cf     = ws + 3*PF;           // FIELD  (zero-span = 3*PF + FIELD)
    float* x0     = cf + FIELD;          // FIELD
    float* ytick  = x0 + FIELD;          // FIELD
    float* w2     = ytick + FIELD;       // 294912
    float* psum   = w2 + 294912;         // 131072
    float* psumsq = psum + 131072;       // 131072
    float* scale  = psumsq + 131072;     // 64
    float* shift  = scale + 64;          // 64
    float* xmean  = shift + 64;          // 8192
    float* hfpart = xmean + 8192;        // 32768
    float* ytpart = hfpart + 32768;      // 8192
    float* featpart = ytpart + 8192;     // 131072
    float* hQ     = featpart + 131072;   // 512
    float* cQ     = hQ + 512;
    float* hR     = cQ + 512;
    float* cR     = hR + 512;
    float* Pg     = cR + 512;            // 32768
    float* Kg     = Pg + 32768;          // 32768

    hipLaunchKernelGGL(k_w2, dim3(1152), dim3(256), 0, stream, clstm_w, w2);
    hipLaunchKernelGGL(k_proj, dim3(16,128), dim3(256), 0, stream, x, proj_w, x0, psum, psumsq);
    hipLaunchKernelGGL(k_bnfinal, dim3(1), dim3(64), 0, stream, psum, psumsq, bn_g, bn_b, scale, shift, xmean);
    hipLaunchKernelGGL(k_zero, dim3(9176), dim3(256), 0, stream, ws);   // yhat_p|hfA_p|hfB_p|cf
    hipLaunchKernelGGL(k_init, dim3(8192), dim3(256), 0, stream, scale, shift, x0, yhat_p, P_init, Pg, hQ, cQ, hR, cR);

    for (int t = 0; t < 16; ++t){
        float* hf_in  = (t & 1) ? hfB_p : hfA_p;
        float* hf_out = (t & 1) ? hfA_p : hfB_p;
        hipLaunchKernelGGL(k_conv, dim3(32,8), dim3(256), 0, stream,
                           yhat_p, hf_in, hf_out, cf, w2, clstm_b, hfpart);
        hipLaunchKernelGGL(k_ytick, dim3(16,8), dim3(256), 0, stream,
                           hf_out, fcf_w, fcf_b, ytick, ytpart);
        hipLaunchKernelGGL(k_small, dim3(8), dim3(256), 0, stream, t,
                           hfpart, ytpart, xmean, fcF_w, fcF_b,
                           lq_wih, lq_whh, lq_bih, lq_bhh,
                           lr_wih, lr_whh, lr_bih, lr_bhh,
                           fcQ_w, fcQ_b, fcR_w, fcR_b,
                           hQ, cQ, hR, cR, Pg, Kg);
        hipLaunchKernelGGL(k_apply, dim3(16,8), dim3(256), 0, stream, t,
                           ytick, x0, Kg, yhat_p, featpart);
    }
    hipLaunchKernelGGL(k_head, dim3(128), dim3(64), 0, stream,
                       featpart, fc_w, fc_b, fco_w, fco_b, fca_w, fca_b, out);
}

// Round 6
// 6530.254 us; speedup vs baseline: 1.9652x; 1.9652x over previous
//
#include <hip/hip_runtime.h>
#include <math.h>

// Problem constants: B=8, S=16, CIN=128, H=W=64, D=64
// Padded field layout for conv inputs: [b][c][66 rows][72 cols], value(x,y) at [y+1][x+4],
// borders zero. PF = 8*64*66*72 = 2,433,024 floats.

__device__ __forceinline__ float sigf(float x){ return 1.0f/(1.0f + expf(-x)); }

#define FMA4(A, W, V0, V1, V2, V3) { (A).x += (W)*(V0); (A).y += (W)*(V1); (A).z += (W)*(V2); (A).w += (W)*(V3); }

// ---------------------------------------------------------------------------
// reshape clstm_w (256,128,3,3) -> w3[dh][ic*9+k][g*32+dd]  (dh = d-half)
// oc = g*64 + dh*32 + dd
__global__ __launch_bounds__(256) void k_w3(const float* __restrict__ cw, float* __restrict__ w3){
    int idx = blockIdx.x*256 + threadIdx.x;
    if (idx < 294912){
        int ddp = idx & 127;            // g*32+dd
        int rkd = idx >> 7;             // dh*1152 + (ic*9+k)
        int dh  = rkd / 1152;
        int rk  = rkd - dh*1152;
        int oc  = (ddp >> 5)*64 + dh*32 + (ddp & 31);
        w3[idx] = cw[oc*1152 + rk];
    }
}

// ---------------------------------------------------------------------------
// 1x1 proj conv + BN partial sums. Writes raw t==0 slice into x0 buffer.
__global__ __launch_bounds__(256) void k_proj(const float* __restrict__ x, const float* __restrict__ pw,
                                              float* __restrict__ x0raw, float* __restrict__ psum,
                                              float* __restrict__ psumsq){
    __shared__ __align__(16) float smem[8192];
    const int tile = blockIdx.x;
    const int n    = blockIdx.y;
    const int tid  = threadIdx.x;
    const int pj = tid & 63, dg = tid >> 6;

    for (int r = tid; r < 8192; r += 256){
        int c = r >> 6, d = r & 63;
        smem[r] = pw[d*128 + c];
    }
    __syncthreads();

    const int p0 = tile*256 + pj*4;
    float4 acc[16];
#pragma unroll
    for (int i=0;i<16;i++) acc[i] = make_float4(0.f,0.f,0.f,0.f);

    const float* xb = x + (((size_t)n) << 19) + p0;
    for (int c = 0; c < 128; ++c){
        float4 xv = *(const float4*)(xb + ((size_t)c << 12));
        const float4* wr = (const float4*)(smem + c*64 + dg*16);
#pragma unroll
        for (int q=0;q<4;++q){
            float4 w4 = wr[q];
            FMA4(acc[q*4+0], w4.x, xv.x, xv.y, xv.z, xv.w);
            FMA4(acc[q*4+1], w4.y, xv.x, xv.y, xv.z, xv.w);
            FMA4(acc[q*4+2], w4.z, xv.x, xv.y, xv.z, xv.w);
            FMA4(acc[q*4+3], w4.w, xv.x, xv.y, xv.z, xv.w);
        }
    }

    const int t = n & 15, b = n >> 4;
    if (t == 0){
#pragma unroll
        for (int i=0;i<16;i++){
            int dd = dg*16 + i;
            *(float4*)(x0raw + (((size_t)(b*64 + dd)) << 12) + p0) = acc[i];
        }
    }
    float ls[16], lss[16];
#pragma unroll
    for (int i=0;i<16;i++){
        float4 a = acc[i];
        ls[i]  = a.x + a.y + a.z + a.w;
        lss[i] = a.x*a.x + a.y*a.y + a.z*a.z + a.w*a.w;
    }
    __syncthreads();
#pragma unroll
    for (int i=0;i<16;i++) smem[pj*65 + dg*16 + i] = ls[i];
    __syncthreads();
    if (tid < 64){
        float s = 0.f;
        for (int p=0;p<64;p++) s += smem[p*65 + tid];
        psum[((n*16 + tile) << 6) + tid] = s;
    }
    __syncthreads();
#pragma unroll
    for (int i=0;i<16;i++) smem[pj*65 + dg*16 + i] = lss[i];
    __syncthreads();
    if (tid < 64){
        float s = 0.f;
        for (int p=0;p<64;p++) s += smem[p*65 + tid];
        psumsq[((n*16 + tile) << 6) + tid] = s;
    }
}

// ---------------------------------------------------------------------------
__global__ __launch_bounds__(64) void k_bnfinal(const float* __restrict__ psum, const float* __restrict__ psumsq,
                                                const float* __restrict__ gamma, const float* __restrict__ beta,
                                                float* __restrict__ scale, float* __restrict__ shift,
                                                float* __restrict__ xmean){
    const int d = threadIdx.x;
    double gs = 0.0, gss = 0.0;
    for (int n=0;n<128;n++){
        float s = 0.f, ss = 0.f;
        for (int tl=0;tl<16;tl++){
            s  += psum  [((n*16+tl)<<6) + d];
            ss += psumsq[((n*16+tl)<<6) + d];
        }
        gs += (double)s; gss += (double)ss;
    }
    double mu  = gs  / 524288.0;
    double var = gss / 524288.0 - mu*mu;
    double sc  = (double)gamma[d] / sqrt(var + 1e-5);
    float scf = (float)sc;
    float shf = (float)((double)beta[d] - mu*sc);
    scale[d] = scf; shift[d] = shf;
    for (int n=0;n<128;n++){
        float s = 0.f;
        for (int tl=0;tl<16;tl++) s += psum[((n*16+tl)<<6) + d];
        xmean[(n<<6) + d] = (s * (1.f/4096.f)) * scf + shf;
    }
}

// ---------------------------------------------------------------------------
// Zero a float4-multiple region (yhat_p | hfA_p | hfB_p | cf, contiguous).
__global__ __launch_bounds__(256) void k_zero(float* __restrict__ z){
    size_t i = ((size_t)blockIdx.x*256 + threadIdx.x)*4;
    *(float4*)(z + i) = make_float4(0.f,0.f,0.f,0.f);
}

// ---------------------------------------------------------------------------
// Apply BN to x0 (in place), write yhat_p interior, init states, P=P_init.
__global__ __launch_bounds__(256) void k_init(const float* __restrict__ scale, const float* __restrict__ shift,
                                              float* __restrict__ x0, float* __restrict__ yhat_p,
                                              const float* __restrict__ Pinit, float* __restrict__ Pg,
                                              float* __restrict__ hQ, float* __restrict__ cQ,
                                              float* __restrict__ hR, float* __restrict__ cR){
    size_t idx = (size_t)blockIdx.x*256 + threadIdx.x;   // 2,097,152 total
    int d = (int)((idx >> 12) & 63);
    float v = x0[idx]*scale[d] + shift[d];
    x0[idx] = v;
    int b = (int)(idx >> 18), r = (int)((idx >> 6) & 63), xx = (int)(idx & 63);
    yhat_p[(((size_t)(b*64 + d))*66 + r + 1)*72 + xx + 4] = v;
    if (idx < 512){ hQ[idx]=0.f; cQ[idx]=0.f; hR[idx]=0.f; cR[idx]=0.f; }
    if (idx < 32768) Pg[idx] = Pinit[idx & 4095];
}

// ---------------------------------------------------------------------------
// ConvLSTM step. grid (64 rows, 2 d-halves, 8 b) = 1024 blocks, 256 thr,
// ~4 blocks/CU (LDS 34.9 KB, VGPR<=128) -> 4 waves/SIMD for latency hiding.
// Thread (compute): pxq=tid&15 (4 px), ocg=tid>>4 (8 consecutive oc' of 128).
// oc' = g*32+dd -> global oc = g*64 + dh*32 + dd (w3 pre-transposed).
// Synchronous 2-barrier chunk loop (4 ic/chunk), round-3 style.
// Gates re-assembled via one-time zc LDS exchange; gating thread: 32 d x 8 px.
__global__ __launch_bounds__(256,4) void k_conv(const float* __restrict__ yhat_p, const float* __restrict__ hfin_p,
                                                float* __restrict__ hfout_p, float* __restrict__ cf,
                                                const float* __restrict__ w3, const float* __restrict__ cb,
                                                float* __restrict__ hfpart){
    // LDS union: [staging: wbuf 4608 | ibuf 864] vs [zc 64*132=8448]; red at 8448.
    __shared__ __align__(16) float smem[8712];
    const int IB = 4608, RED = 8448;
    const int row = blockIdx.x;
    const int dh  = blockIdx.y;
    const int b   = blockIdx.z;
    const int tid = threadIdx.x;
    const int pxq = tid & 15;
    const int ocg = tid >> 4;
    const int px0 = pxq*4;
    const int ocb = ocg*8;

    float4 acc[8];
#pragma unroll
    for (int i=0;i<8;i++) acc[i] = make_float4(0.f,0.f,0.f,0.f);

    const float4* w3c = (const float4*)(w3 + (size_t)dh*147456);   // [1152 rk][128] as float4[rk*32]

    for (int icc = 0; icc < 32; ++icc){
        __syncthreads();
        // ---- stage chunk: weights 1152 float4 (contiguous) + inputs 216 float4 ----
        {
            const float4* wsrc = w3c + (size_t)icc*1152;
#pragma unroll
            for (int j=0;j<6;++j){
                int s = tid + j*256;
                if (s < 1152){
                    *(float4*)(smem + s*4) = wsrc[s];
                } else if (s < 1368){
                    int si  = s - 1152;          // float4 index into ibuf [4 icl][3 r][18]
                    int icl = si / 54;
                    int rem = si - icl*54;
                    int r   = rem / 18;
                    int x4  = rem - r*18;
                    int ic  = icc*4 + icl;
                    const float* f = (ic < 64) ? yhat_p : hfin_p;
                    *(float4*)(smem + IB + si*4) =
                        *(const float4*)(f + (((size_t)(b*64 + (ic & 63)))*66 + row + r)*72 + x4*4);
                }
            }
        }
        __syncthreads();
        // ---- compute ----
#pragma unroll
        for (int icl = 0; icl < 4; ++icl){
            float v[3][6];
#pragma unroll
            for (int ky=0; ky<3; ++ky){
                const float* vp = smem + IB + icl*216 + ky*72 + px0;
                v[ky][0] = vp[3];
                float4 va = *(const float4*)(vp + 4);
                v[ky][1]=va.x; v[ky][2]=va.y; v[ky][3]=va.z; v[ky][4]=va.w;
                v[ky][5] = vp[8];
            }
#pragma unroll
            for (int k=0;k<9;++k){
                const int ky = k/3, kx = k - ky*3;
                const float* wr = smem + (icl*9 + k)*128 + ocb;
                float4 wa = *(const float4*)(wr);
                float4 wb4 = *(const float4*)(wr + 4);
                const float v0=v[ky][kx+0], v1=v[ky][kx+1], v2=v[ky][kx+2], v3=v[ky][kx+3];
                FMA4(acc[0], wa.x, v0,v1,v2,v3);
                FMA4(acc[1], wa.y, v0,v1,v2,v3);
                FMA4(acc[2], wa.z, v0,v1,v2,v3);
                FMA4(acc[3], wa.w, v0,v1,v2,v3);
                FMA4(acc[4], wb4.x, v0,v1,v2,v3);
                FMA4(acc[5], wb4.y, v0,v1,v2,v3);
                FMA4(acc[6], wb4.z, v0,v1,v2,v3);
                FMA4(acc[7], wb4.w, v0,v1,v2,v3);
            }
        }
    }

    // ---- zc exchange: [64 px][132] (pad) ----
    __syncthreads();
#pragma unroll
    for (int o=0;o<8;++o){
        smem[(px0+0)*132 + ocb + o] = acc[o].x;
        smem[(px0+1)*132 + ocb + o] = acc[o].y;
        smem[(px0+2)*132 + ocb + o] = acc[o].z;
        smem[(px0+3)*132 + ocb + o] = acc[o].w;
    }
    __syncthreads();

    // ---- gating: thread = (d_local = tid&31, pxg = tid>>5 -> 8 px) ----
    const int dl  = tid & 31;
    const int pxg = tid >> 5;
    const int dg  = dh*32 + dl;
    const float biv = cb[dg], bfv = cb[64+dg], bov = cb[128+dg], bgv = cb[192+dg];
    float hsum = 0.f;
    const size_t gidx = (((size_t)(b*64 + dg)) << 12) + row*64 + pxg*8;
    const size_t pidx = (((size_t)(b*64 + dg))*66 + row + 1)*72 + pxg*8 + 4;
#pragma unroll
    for (int h2=0; h2<2; ++h2){
        float4 c_old = *(const float4*)(cf + gidx + h2*4);
        float ca[4] = {c_old.x, c_old.y, c_old.z, c_old.w};
        float c2a[4], ha[4];
#pragma unroll
        for (int e=0;e<4;++e){
            int px = pxg*8 + h2*4 + e;
            float zi = smem[px*132 +      dl] + biv;
            float zf = smem[px*132 + 32 + dl] + bfv;
            float zo = smem[px*132 + 64 + dl] + bov;
            float zg = smem[px*132 + 96 + dl] + bgv;
            c2a[e] = sigf(zf)*ca[e] + sigf(zi)*tanhf(zg);
            ha[e]  = sigf(zo)*tanhf(c2a[e]);
            hsum  += ha[e];
        }
        float4 c2 = make_float4(c2a[0],c2a[1],c2a[2],c2a[3]);
        float4 hh = make_float4(ha[0],ha[1],ha[2],ha[3]);
        *(float4*)(cf + gidx + h2*4) = c2;
        *(float4*)(hfout_p + pidx + h2*4) = hh;
    }
    smem[RED + pxg*33 + dl] = hsum;
    __syncthreads();
    if (tid < 32){
        float s = 0.f;
#pragma unroll
        for (int q=0;q<8;q++) s += smem[RED + q*33 + tid];
        hfpart[((b*64 + row) << 6) + dh*32 + tid] = s;
    }
}

// ---------------------------------------------------------------------------
// y_tick = fcf(hf) per position + spatial partial sums. grid (16,8), block 256.
// Reads hf from the PADDED field.
__global__ __launch_bounds__(256) void k_ytick(const float* __restrict__ hf_p, const float* __restrict__ fw,
                                               const float* __restrict__ fb, float* __restrict__ ytick,
                                               float* __restrict__ ytpart){
    __shared__ __align__(16) float wsm[4096];
    __shared__ float red[4160];
    const int tile = blockIdx.x;
    const int b    = blockIdx.y;
    const int tid  = threadIdx.x;
    const int pj = tid & 63, dg = tid >> 6;

    for (int r = tid; r < 4096; r += 256){
        int e = r >> 6, dd = r & 63;
        wsm[r] = fw[dd*64 + e];
    }
    __syncthreads();

    const int p0 = tile*256 + pj*4;
    const int r = p0 >> 6, xx = p0 & 63;
    float4 acc[16];
#pragma unroll
    for (int i=0;i<16;i++) acc[i] = make_float4(0.f,0.f,0.f,0.f);

    const float* hb = hf_p + (((size_t)(b*64))*66 + r + 1)*72 + xx + 4;
    for (int e = 0; e < 64; ++e){
        float4 hv = *(const float4*)(hb + (size_t)e*4752);   // 66*72
        const float4* wr = (const float4*)(wsm + e*64 + dg*16);
#pragma unroll
        for (int q=0;q<4;++q){
            float4 w4 = wr[q];
            FMA4(acc[q*4+0], w4.x, hv.x, hv.y, hv.z, hv.w);
            FMA4(acc[q*4+1], w4.y, hv.x, hv.y, hv.z, hv.w);
            FMA4(acc[q*4+2], w4.z, hv.x, hv.y, hv.z, hv.w);
            FMA4(acc[q*4+3], w4.w, hv.x, hv.y, hv.z, hv.w);
        }
    }
    float ls[16];
#pragma unroll
    for (int i=0;i<16;i++){
        int dd = dg*16 + i;
        float bv = fb[dd];
        acc[i].x += bv; acc[i].y += bv; acc[i].z += bv; acc[i].w += bv;
        *(float4*)(ytick + (((size_t)(b*64 + dd)) << 12) + p0) = acc[i];
        ls[i] = acc[i].x + acc[i].y + acc[i].z + acc[i].w;
    }
#pragma unroll
    for (int i=0;i<16;i++) red[pj*65 + dg*16 + i] = ls[i];
    __syncthreads();
    if (tid < 64){
        float s = 0.f;
        for (int p=0;p<64;p++) s += red[p*65 + tid];
        ytpart[((b*16 + tile) << 6) + tid] = s;
    }
}

// ---------------------------------------------------------------------------
// Per-step small ops + Kalman update. grid 8 (b), block 256.
__global__ __launch_bounds__(256) void k_small(int t,
        const float* __restrict__ hfpart, const float* __restrict__ ytpart, const float* __restrict__ xmean,
        const float* __restrict__ fcF_w, const float* __restrict__ fcF_b,
        const float* __restrict__ lq_wih, const float* __restrict__ lq_whh,
        const float* __restrict__ lq_bih, const float* __restrict__ lq_bhh,
        const float* __restrict__ lr_wih, const float* __restrict__ lr_whh,
        const float* __restrict__ lr_bih, const float* __restrict__ lr_bhh,
        const float* __restrict__ fcQ_w, const float* __restrict__ fcQ_b,
        const float* __restrict__ fcR_w, const float* __restrict__ fcR_b,
        float* __restrict__ hQ, float* __restrict__ cQ, float* __restrict__ hR, float* __restrict__ cR,
        float* __restrict__ Pg, float* __restrict__ Kg){
    const int b = blockIdx.x, tid = threadIdx.x;
    __shared__ __align__(16) float aug[64*132];
    __shared__ __align__(16) float Pl[4096];
    __shared__ float hfm[64], ytm[64], xm[64], Fv[64], Qd[64], Rd[64], rds[64];
    __shared__ float hq_s[64], cq_s[64], hr_s[64], cr_s[64];
    __shared__ float gq[256], gr[256];

    if (tid < 64){
        float s = 0.f;
        for (int r=0;r<64;r++) s += hfpart[((b*64 + r) << 6) + tid];
        hfm[tid] = s * (1.f/4096.f);
        float s2 = 0.f;
        for (int r=0;r<16;r++) s2 += ytpart[((b*16 + r) << 6) + tid];
        ytm[tid] = s2 * (1.f/4096.f);
        xm[tid] = xmean[((b*16 + t) << 6) + tid];
        hq_s[tid] = hQ[b*64+tid]; cq_s[tid] = cQ[b*64+tid];
        hr_s[tid] = hR[b*64+tid]; cr_s[tid] = cR[b*64+tid];
    }
    __syncthreads();
    {
        int j = tid;
        float aq = lq_bih[j] + lq_bhh[j];
        float ar = lr_bih[j] + lr_bhh[j];
        for (int e=0;e<64;e++){
            aq += lq_wih[j*64+e]*ytm[e] + lq_whh[j*64+e]*hq_s[e];
            ar += lr_wih[j*64+e]*xm[e]  + lr_whh[j*64+e]*hr_s[e];
        }
        gq[j] = aq; gr[j] = ar;
    }
    if (tid < 64){
        float a = fcF_b[tid];
        for (int e=0;e<64;e++) a += fcF_w[tid*64+e]*hfm[e];
        Fv[tid] = a;
    }
    __syncthreads();
    if (tid < 64){   // lstm_cell gate order: i, f, g, o
        int dd = tid;
        float gi = gq[dd], gf = gq[64+dd], gg = gq[128+dd], go = gq[192+dd];
        float c2 = sigf(gf)*cq_s[dd] + sigf(gi)*tanhf(gg);
        float h2 = sigf(go)*tanhf(c2);
        cq_s[dd] = c2; hq_s[dd] = h2;
        gi = gr[dd]; gf = gr[64+dd]; gg = gr[128+dd]; go = gr[192+dd];
        c2 = sigf(gf)*cr_s[dd] + sigf(gi)*tanhf(gg);
        h2 = sigf(go)*tanhf(c2);
        cr_s[dd] = c2; hr_s[dd] = h2;
    }
    __syncthreads();
    if (tid < 64){
        float aq_ = fcQ_b[tid], ar_ = fcR_b[tid];
        for (int e=0;e<64;e++){ aq_ += fcQ_w[tid*64+e]*hq_s[e]; ar_ += fcR_w[tid*64+e]*hr_s[e]; }
        Qd[tid] = expf(aq_); Rd[tid] = expf(ar_);
        hQ[b*64+tid] = hq_s[tid]; cQ[b*64+tid] = cq_s[tid];
        hR[b*64+tid] = hr_s[tid]; cR[b*64+tid] = cr_s[tid];
    }
    __syncthreads();
    // P = P*FF + diag(Qd); aug = [A=P+diag(Rd) | P]
    for (int r = tid; r < 4096; r += 256){
        int i = r >> 6, j = r & 63;
        float p = Pg[((size_t)b << 12) + r] * Fv[i]*Fv[j] + (i==j ? Qd[i] : 0.f);
        Pl[r] = p;
        aug[i*132 + 64 + j] = p;
        aug[i*132 + j]      = p + (i==j ? Rd[i] : 0.f);
    }
    __syncthreads();
    const int r_ = tid & 63, cq_ = tid >> 6;
    for (int k = 0; k < 64; ++k){
        float akk = aug[k*132 + k];
        float f = aug[r_*132 + k] / akk;
        if (r_ != k){
#pragma unroll
            for (int u = 0; u < 8; ++u){
                int c4 = cq_*32 + u*4;
                if (c4 + 3 > k){
                    float4 pv = *(const float4*)(aug + k*132 + c4);
                    float4 av = *(const float4*)(aug + r_*132 + c4);
                    av.x = (c4+0 > k) ? av.x - f*pv.x : av.x;
                    av.y = (c4+1 > k) ? av.y - f*pv.y : av.y;
                    av.z = (c4+2 > k) ? av.z - f*pv.z : av.z;
                    av.w = (c4+3 > k) ? av.w - f*pv.w : av.w;
                    *(float4*)(aug + r_*132 + c4) = av;
                }
            }
        }
        __syncthreads();
    }
    if (tid < 64) rds[tid] = 1.0f / aug[tid*132 + tid];
    __syncthreads();
    {
        const int i = tid >> 2, jq = tid & 3;
        float4 tv[4];
#pragma unroll
        for (int q=0;q<4;++q) tv[q] = *(const float4*)(Pl + i*64 + jq*16 + q*4);
        for (int m=0;m<64;++m){
            float kim = aug[m*132 + 64 + i] * rds[m];
#pragma unroll
            for (int q=0;q<4;++q){
                float4 pv = *(const float4*)(Pl + m*64 + jq*16 + q*4);
                tv[q].x -= kim*pv.x; tv[q].y -= kim*pv.y; tv[q].z -= kim*pv.z; tv[q].w -= kim*pv.w;
            }
        }
#pragma unroll
        for (int q=0;q<4;++q) *(float4*)(aug + i*132 + jq*16 + q*4) = tv[q];
    }
    __syncthreads();
    {
        const int i = tid >> 2, jq = tid & 3;
        float4 a2[4];
#pragma unroll
        for (int q=0;q<4;++q) a2[q] = *(const float4*)(aug + i*132 + jq*16 + q*4);
        for (int m=0;m<64;++m){
            float t1im = aug[i*132 + m];
            float kim  = aug[m*132 + 64 + i] * rds[m];
            float coef = rds[m] * (kim * Rd[m] - t1im);
#pragma unroll
            for (int q=0;q<4;++q){
                float4 yv = *(const float4*)(aug + m*132 + 64 + jq*16 + q*4);
                a2[q].x += coef*yv.x; a2[q].y += coef*yv.y; a2[q].z += coef*yv.z; a2[q].w += coef*yv.w;
            }
        }
        size_t base = ((size_t)b << 12) + (size_t)i*64;
#pragma unroll
        for (int q=0;q<4;++q) *(float4*)(Pg + base + jq*16 + q*4) = a2[q];
#pragma unroll
        for (int q=0;q<4;++q){
#pragma unroll
            for (int e=0;e<4;++e){
                int j = jq*16 + q*4 + e;
                Kg[base + j] = aug[j*132 + 64 + i] * rds[j];
            }
        }
    }
}

// ---------------------------------------------------------------------------
// y_hat = y_tick + K(x0 - y_tick); writes PADDED yhat + spatial partial sums.
__global__ __launch_bounds__(256) void k_apply(int t, const float* __restrict__ ytick,
                                               const float* __restrict__ x0, const float* __restrict__ Kg,
                                               float* __restrict__ yhat_p, float* __restrict__ featpart){
    __shared__ __align__(16) float kt[4096];
    __shared__ float red[4160];
    const int tile = blockIdx.x;
    const int b    = blockIdx.y;
    const int tid  = threadIdx.x;
    const int pj = tid & 63, dg = tid >> 6;

    for (int r = tid; r < 4096; r += 256){
        int i = r >> 6, j = r & 63;
        kt[j*64 + i] = Kg[((size_t)b << 12) + r];
    }
    __syncthreads();

    const int p0 = tile*256 + pj*4;
    const int r = p0 >> 6, xx = p0 & 63;
    float4 acc[16];
#pragma unroll
    for (int i=0;i<16;i++) acc[i] = make_float4(0.f,0.f,0.f,0.f);

    for (int j = 0; j < 64; ++j){
        size_t gi = (((size_t)(b*64 + j)) << 12) + p0;
        float4 xv = *(const float4*)(x0 + gi);
        float4 yv = *(const float4*)(ytick + gi);
        float u0 = xv.x - yv.x, u1 = xv.y - yv.y, u2 = xv.z - yv.z, u3 = xv.w - yv.w;
        const float4* wr = (const float4*)(kt + j*64 + dg*16);
#pragma unroll
        for (int q=0;q<4;++q){
            float4 k4 = wr[q];
            FMA4(acc[q*4+0], k4.x, u0,u1,u2,u3);
            FMA4(acc[q*4+1], k4.y, u0,u1,u2,u3);
            FMA4(acc[q*4+2], k4.z, u0,u1,u2,u3);
            FMA4(acc[q*4+3], k4.w, u0,u1,u2,u3);
        }
    }
    float ls[16];
#pragma unroll
    for (int i=0;i<16;i++){
        int dd = dg*16 + i;
        size_t gi = (((size_t)(b*64 + dd)) << 12) + p0;
        float4 yv = *(const float4*)(ytick + gi);
        float4 o;
        o.x = yv.x + acc[i].x; o.y = yv.y + acc[i].y; o.z = yv.z + acc[i].z; o.w = yv.w + acc[i].w;
        *(float4*)(yhat_p + (((size_t)(b*64 + dd))*66 + r + 1)*72 + xx + 4) = o;
        ls[i] = o.x + o.y + o.z + o.w;
    }
#pragma unroll
    for (int i=0;i<16;i++) red[pj*65 + dg*16 + i] = ls[i];
    __syncthreads();
    if (tid < 64){
        float s = 0.f;
        for (int p=0;p<64;p++) s += red[p*65 + tid];
        featpart[(((size_t)((t*8 + b)*16 + tile)) << 6) + tid] = s;
    }
}

// ---------------------------------------------------------------------------
__global__ __launch_bounds__(64) void k_head(const float* __restrict__ featpart,
                                             const float* __restrict__ fc_w, const float* __restrict__ fc_b,
                                             const float* __restrict__ fco_w, const float* __restrict__ fco_b,
                                             const float* __restrict__ fca_w, const float* __restrict__ fca_b,
                                             float* __restrict__ out){
    const int bt = blockIdx.x;
    const int b = bt >> 4, t = bt & 15;
    __shared__ float fs[64];
    const int i = threadIdx.x;
    float s = 0.f;
    for (int tile=0;tile<16;tile++) s += featpart[(((size_t)((t*8 + b)*16 + tile)) << 6) + i];
    fs[i] = s * (1.f/4096.f);
    __syncthreads();
    float a = fc_b[i];
    for (int e=0;e<64;e++) a += fc_w[i*64+e]*fs[e];
    a = fmaxf(a, 0.f);
    float po = a * fco_w[i];
    float pa = a * fca_w[i];
    for (int off=32; off; off >>= 1){ po += __shfl_down(po, off); pa += __shfl_down(pa, off); }
    if (i == 0){
        out[bt]       = po + fco_b[0];
        out[128 + bt] = pa + fca_b[0];
    }
}

// ---------------------------------------------------------------------------
extern "C" void kernel_launch(void* const* d_in, const int* in_sizes, int n_in,
                              void* d_out, int out_size, void* d_ws, size_t ws_size,
                              hipStream_t stream){
    const float* x       = (const float*)d_in[0];
    const float* proj_w  = (const float*)d_in[1];
    const float* bn_g    = (const float*)d_in[2];
    const float* bn_b    = (const float*)d_in[3];
    const float* clstm_w = (const float*)d_in[4];
    const float* clstm_b = (const float*)d_in[5];
    const float* lq_wih  = (const float*)d_in[6];
    const float* lq_whh  = (const float*)d_in[7];
    const float* lq_bih  = (const float*)d_in[8];
    const float* lq_bhh  = (const float*)d_in[9];
    const float* lr_wih  = (const float*)d_in[10];
    const float* lr_whh  = (const float*)d_in[11];
    const float* lr_bih  = (const float*)d_in[12];
    const float* lr_bhh  = (const float*)d_in[13];
    const float* fcf_w   = (const float*)d_in[14];
    const float* fcf_b   = (const float*)d_in[15];
    const float* fcF_w   = (const float*)d_in[16];
    const float* fcF_b   = (const float*)d_in[17];
    const float* fcQ_w   = (const float*)d_in[18];
    const float* fcQ_b   = (const float*)d_in[19];
    const float* fcR_w   = (const float*)d_in[20];
    const float* fcR_b   = (const float*)d_in[21];
    const float* P_init  = (const float*)d_in[22];
    const float* fc_w    = (const float*)d_in[23];
    const float* fc_b    = (const float*)d_in[24];
    const float* fco_w   = (const float*)d_in[25];
    const float* fco_b   = (const float*)d_in[26];
    const float* fca_w   = (const float*)d_in[27];
    const float* fca_b   = (const float*)d_in[28];
    float* out = (float*)d_out;
    float* ws  = (float*)d_ws;

    const size_t PF    = 2433024;        // 8*64*66*72 padded field
    const size_t FIELD = 2097152;        // 8*64*4096
    float* yhat_p = ws;                  // PF
    float* hfA_p  = ws + PF;             // PF
    float* hfB_p  = ws + 2*PF;           // PF
    float* cf     = ws + 3*PF;           // FIELD  (zero-span = 3*PF + FIELD)
    float* x0     = cf + FIELD;          // FIELD
    float* ytick  = x0 + FIELD;          // FIELD
    float* w3     = ytick + FIELD;       // 294912
    float* psum   = w3 + 294912;         // 131072
    float* psumsq = psum + 131072;       // 131072
    float* scale  = psumsq + 131072;     // 64
    float* shift  = scale + 64;          // 64
    float* xmean  = shift + 64;          // 8192
    float* hfpart = xmean + 8192;        // 32768
    float* ytpart = hfpart + 32768;      // 8192
    float* featpart = ytpart + 8192;     // 131072
    float* hQ     = featpart + 131072;   // 512
    float* cQ     = hQ + 512;
    float* hR     = cQ + 512;
    float* cR     = hR + 512;
    float* Pg     = cR + 512;            // 32768
    float* Kg     = Pg + 32768;          // 32768

    hipLaunchKernelGGL(k_w3, dim3(1152), dim3(256), 0, stream, clstm_w, w3);
    hipLaunchKernelGGL(k_proj, dim3(16,128), dim3(256), 0, stream, x, proj_w, x0, psum, psumsq);
    hipLaunchKernelGGL(k_bnfinal, dim3(1), dim3(64), 0, stream, psum, psumsq, bn_g, bn_b, scale, shift, xmean);
    hipLaunchKernelGGL(k_zero, dim3(9176), dim3(256), 0, stream, ws);   // yhat_p|hfA_p|hfB_p|cf
    hipLaunchKernelGGL(k_init, dim3(8192), dim3(256), 0, stream, scale, shift, x0, yhat_p, P_init, Pg, hQ, cQ, hR, cR);

    for (int t = 0; t < 16; ++t){
        float* hf_in  = (t & 1) ? hfB_p : hfA_p;
        float* hf_out = (t & 1) ? hfA_p : hfB_p;
        hipLaunchKernelGGL(k_conv, dim3(64,2,8), dim3(256), 0, stream,
                           yhat_p, hf_in, hf_out, cf, w3, clstm_b, hfpart);
        hipLaunchKernelGGL(k_ytick, dim3(16,8), dim3(256), 0, stream,
                           hf_out, fcf_w, fcf_b, ytick, ytpart);
        hipLaunchKernelGGL(k_small, dim3(8), dim3(256), 0, stream, t,
                           hfpart, ytpart, xmean, fcF_w, fcF_b,
                           lq_wih, lq_whh, lq_bih, lq_bhh,
                           lr_wih, lr_whh, lr_bih, lr_bhh,
                           fcQ_w, fcQ_b, fcR_w, fcR_b,
                           hQ, cQ, hR, cR, Pg, Kg);
        hipLaunchKernelGGL(k_apply, dim3(16,8), dim3(256), 0, stream, t,
                           ytick, x0, Kg, yhat_p, featpart);
    }
    hipLaunchKernelGGL(k_head, dim3(128), dim3(64), 0, stream,
                       featpart, fc_w, fc_b, fco_w, fco_b, fca_w, fca_b, out);
}